// Round 3
// baseline (171.315 us; speedup 1.0000x reference)
//
#include <hip/hip_runtime.h>

// AnomalyAttention forward, MI355X gfx950.
// B=8, N=1024, D=1024. Out = [Z (8*1024*1024 f32), P (8*1024*1024 f32)].
// Round 3: 3-buffer LDS pipeline (prefetch distance 2 K-tiles, vmcnt(6)),
// LDS-coalesced f32 epilogue. Tile 128x256, BK=64, 8 waves, XOR-swizzled LDS.

typedef __attribute__((ext_vector_type(8))) short bf16x8;
typedef __attribute__((ext_vector_type(4))) float f32x4;
typedef unsigned short ushort_t;

#define DI __device__ __forceinline__

constexpr long NN = 1024L * 1024L;
constexpr long ND = 1024L * 1024L;

DI ushort_t f2bf(float f) {  // round-to-nearest-even f32 -> bf16 bits
    unsigned int u = __float_as_uint(f);
    u = u + 0x7fffu + ((u >> 16) & 1u);
    return (ushort_t)(u >> 16);
}

// ---------------------------------------------------------------------------
// Pipelined GEMM: C[M,N] = A[M,K=1024] * Bt[N,K=1024]^T, bf16 in, fp32 acc.
// Tile 128x256, BK=64, 8 waves (2M x 4N), per-wave 64x64 (4x4 16x16x32 frags).
// LDS: 3 buffers x (A[128][64] + B[256][64]) bf16 = 144 KB, XOR-swizzled
//   (byte ^= (row&7)<<4); linear gload_lds dest + inverse-swizzled global src.
// Schedule per K-tile t (2 phases), prefetch distance 2:
//   ph1: ds_read a[2][4]+b[2][0..1]; issue stage B(t+2)x4 -> buf[(t+2)%3];
//        barrier; lgkm(0); setprio1; 16 MFMA (n0,n1); setprio0; barrier
//   ph2: ds_read b[2][2..3]; issue stage A(t+2)x2;
//        barrier; lgkm(0); vmcnt(6 | 0 at tail); setprio1; 16 MFMA; barrier
// vmcnt ledger: tile t+1's 6 loads are the oldest 6 of <=12 outstanding;
// vmcnt(6) at end of t drains exactly them (issued 2 K-tiles earlier).
// Overwrite safety: buf[(t+2)%3] = t-1's data; t-1 reads drained by its
// lgkm(0)s before the t-1-end barrier all waves passed before staging.
// ---------------------------------------------------------------------------
template <int OUT_BF16>
__global__ __launch_bounds__(512, 2)
void gemm3b(const ushort_t* __restrict__ A, const ushort_t* __restrict__ B,
            void* __restrict__ Cout, int ldA, int ldB, int ldC,
            long sA, long sB, long sC, float scale)
{
    __shared__ ushort_t lds[3][24576];   // per buf: A 8192 + B 16384 ushorts
    constexpr int B_OFF = 8192;

    const int tid  = threadIdx.x;
    const int wave = tid >> 6;
    const int lane = tid & 63;
    const int wm   = wave >> 2;   // 0..1
    const int wn   = wave & 3;    // 0..3
    const int gm   = blockIdx.x * 128;
    const int gn   = blockIdx.y * 256;
    const ushort_t* Ab = A + (long)blockIdx.z * sA;
    const ushort_t* Bb = B + (long)blockIdx.z * sB;

    // staging: thread t loads 16B; row in 64-row half = tid>>3,
    // swizzled source col chunk = (tid&7) ^ (row&7)
    const int srow = tid >> 3;
    const int scol = 8 * ((tid & 7) ^ (srow & 7));
    const int sdst = wave * 512;   // wave-uniform LDS dest offset (ushorts)

    auto stageA = [&](int t, int d, int h) {
        const ushort_t* src = Ab + (long)(gm + h * 64 + srow) * ldA + t * 64 + scol;
        __builtin_amdgcn_global_load_lds(
            (const __attribute__((address_space(1))) void*)src,
            (__attribute__((address_space(3))) void*)(&lds[d][h * 4096 + sdst]),
            16, 0, 0);
    };
    auto stageB = [&](int t, int d, int h, int j) {
        const ushort_t* src = Bb + (long)(gn + h * 128 + j * 64 + srow) * ldB + t * 64 + scol;
        __builtin_amdgcn_global_load_lds(
            (const __attribute__((address_space(1))) void*)src,
            (__attribute__((address_space(3))) void*)(&lds[d][B_OFF + h * 8192 + j * 4096 + sdst]),
            16, 0, 0);
    };

    // fragment reads: row = base + (lane&15); swizzle uses row&7 == lane&7
    const int arow = wm * 64 + (lane & 15);
    const int brow = wn * 64 + (lane & 15);
    const int cs0 = (((lane >> 4) * 16) ^ ((lane & 7) << 4)) >> 1;        // ushorts
    const int cs1 = ((64 + (lane >> 4) * 16) ^ ((lane & 7) << 4)) >> 1;

    f32x4 acc[4][4];
#pragma unroll
    for (int m = 0; m < 4; ++m)
#pragma unroll
        for (int n = 0; n < 4; ++n) acc[m][n] = (f32x4){0.f, 0.f, 0.f, 0.f};

    // prologue: tile0 -> buf0, tile1 -> buf1 (6 loads each)
    stageA(0, 0, 0); stageA(0, 0, 1);
    stageB(0, 0, 0, 0); stageB(0, 0, 0, 1); stageB(0, 0, 1, 0); stageB(0, 0, 1, 1);
    stageA(1, 1, 0); stageA(1, 1, 1);
    stageB(1, 1, 0, 0); stageB(1, 1, 0, 1); stageB(1, 1, 1, 0); stageB(1, 1, 1, 1);
    asm volatile("s_waitcnt vmcnt(6)" ::: "memory");   // tile0 resident
    __builtin_amdgcn_s_barrier();
    __builtin_amdgcn_sched_barrier(0);

    int cur = 0;
    for (int t = 0; t < 16; ++t) {
        const int nxt = (cur == 0) ? 2 : cur - 1;      // (t+2)%3
        const ushort_t* la = &lds[cur][0];
        const ushort_t* lb = &lds[cur][B_OFF];

        bf16x8 a[2][4], b[2][4];
        // ---- phase 1 ----
#pragma unroll
        for (int mi = 0; mi < 4; ++mi) {
            a[0][mi] = *(const bf16x8*)&la[(arow + mi * 16) * 64 + cs0];
            a[1][mi] = *(const bf16x8*)&la[(arow + mi * 16) * 64 + cs1];
        }
#pragma unroll
        for (int ni = 0; ni < 2; ++ni) {
            b[0][ni] = *(const bf16x8*)&lb[(brow + ni * 16) * 64 + cs0];
            b[1][ni] = *(const bf16x8*)&lb[(brow + ni * 16) * 64 + cs1];
        }
        if (t < 14) {
            stageB(t + 2, nxt, 0, 0); stageB(t + 2, nxt, 0, 1);
            stageB(t + 2, nxt, 1, 0); stageB(t + 2, nxt, 1, 1);
        }
        __builtin_amdgcn_s_barrier();
        asm volatile("s_waitcnt lgkmcnt(0)" ::: "memory");
        __builtin_amdgcn_sched_barrier(0);
        __builtin_amdgcn_s_setprio(1);
#pragma unroll
        for (int mi = 0; mi < 4; ++mi)
#pragma unroll
            for (int ni = 0; ni < 2; ++ni) {
                acc[mi][ni] = __builtin_amdgcn_mfma_f32_16x16x32_bf16(a[0][mi], b[0][ni], acc[mi][ni], 0, 0, 0);
                acc[mi][ni] = __builtin_amdgcn_mfma_f32_16x16x32_bf16(a[1][mi], b[1][ni], acc[mi][ni], 0, 0, 0);
            }
        __builtin_amdgcn_s_setprio(0);
        __builtin_amdgcn_s_barrier();
        __builtin_amdgcn_sched_barrier(0);

        // ---- phase 2 ----
#pragma unroll
        for (int ni = 2; ni < 4; ++ni) {
            b[0][ni] = *(const bf16x8*)&lb[(brow + ni * 16) * 64 + cs0];
            b[1][ni] = *(const bf16x8*)&lb[(brow + ni * 16) * 64 + cs1];
        }
        if (t < 14) { stageA(t + 2, nxt, 0); stageA(t + 2, nxt, 1); }
        __builtin_amdgcn_s_barrier();
        asm volatile("s_waitcnt lgkmcnt(0)" ::: "memory");
        if (t < 14) asm volatile("s_waitcnt vmcnt(6)" ::: "memory");  // tile t+1 landed
        else        asm volatile("s_waitcnt vmcnt(0)" ::: "memory");
        __builtin_amdgcn_sched_barrier(0);
        __builtin_amdgcn_s_setprio(1);
#pragma unroll
        for (int mi = 0; mi < 4; ++mi)
#pragma unroll
            for (int ni = 2; ni < 4; ++ni) {
                acc[mi][ni] = __builtin_amdgcn_mfma_f32_16x16x32_bf16(a[0][mi], b[0][ni], acc[mi][ni], 0, 0, 0);
                acc[mi][ni] = __builtin_amdgcn_mfma_f32_16x16x32_bf16(a[1][mi], b[1][ni], acc[mi][ni], 0, 0, 0);
            }
        __builtin_amdgcn_s_setprio(0);
        __builtin_amdgcn_s_barrier();
        __builtin_amdgcn_sched_barrier(0);

        cur = (cur == 2) ? 0 : cur + 1;
    }

    // epilogue. C/D layout (verified): col = lane&15, row = (lane>>4)*4 + r
    if (OUT_BF16) {
        ushort_t* el = &lds[0][0];   // [128][256] ushort = 64 KB
#pragma unroll
        for (int mi = 0; mi < 4; ++mi)
#pragma unroll
            for (int ni = 0; ni < 4; ++ni)
#pragma unroll
                for (int r = 0; r < 4; ++r)
                    el[(wm * 64 + mi * 16 + (lane >> 4) * 4 + r) * 256 +
                       wn * 64 + ni * 16 + (lane & 15)] = f2bf(acc[mi][ni][r] * scale);
        __builtin_amdgcn_s_barrier();
        ushort_t* C = (ushort_t*)Cout + (long)blockIdx.z * sC;
#pragma unroll
        for (int rr = 0; rr < 8; ++rr) {
            const int row = rr * 16 + (tid >> 5);
            const int col = (tid & 31) * 8;
            *(bf16x8*)&C[(long)(gm + row) * ldC + gn + col] =
                *(const bf16x8*)&el[row * 256 + col];
        }
    } else {
        // two 64-row halves staged through LDS for coalesced float4 stores
        float* el = (float*)&lds[0][0];   // [64][256] f32 = 64 KB
        float* C  = (float*)Cout + (long)blockIdx.z * sC;
#pragma unroll
        for (int h = 0; h < 2; ++h) {
            if (wm == h) {
#pragma unroll
                for (int mi = 0; mi < 4; ++mi)
#pragma unroll
                    for (int ni = 0; ni < 4; ++ni)
#pragma unroll
                        for (int r = 0; r < 4; ++r)
                            el[(mi * 16 + (lane >> 4) * 4 + r) * 256 +
                               wn * 64 + ni * 16 + (lane & 15)] = acc[mi][ni][r] * scale;
            }
            __builtin_amdgcn_s_barrier();
#pragma unroll
            for (int i = 0; i < 8; ++i) {
                const int cc  = i * 512 + tid;      // 16B chunk id, 0..4095
                const int row = cc >> 6;
                const int c4  = (cc & 63) * 4;
                *(float4*)&C[(long)(gm + h * 64 + row) * ldC + gn + c4] =
                    *(const float4*)&el[row * 256 + c4];
            }
            __builtin_amdgcn_s_barrier();
        }
    }
}

// ---------------------------------------------------------------------------
// elementwise / helper kernels
// ---------------------------------------------------------------------------

// x -> bf16 AND sigma = 3^(sigmoid(5*(x.Ws))+1e-5)-1 in one pass (one wave/row)
__global__ void cvt_x_sigma(const float* __restrict__ x, const float* __restrict__ Ws,
                            ushort_t* __restrict__ xh, float* __restrict__ sigma)
{
    const int row  = blockIdx.x * 4 + (threadIdx.x >> 6);
    const int lane = threadIdx.x & 63;
    const float* xr = x + (long)row * 1024;
    float dot = 0.f;
#pragma unroll
    for (int it = 0; it < 4; ++it) {
        const int i = it * 256 + lane * 4;
        float4 v = *(const float4*)(xr + i);
        float4 w = *(const float4*)(Ws + i);
        dot += v.x * w.x + v.y * w.y + v.z * w.z + v.w * w.w;
        ushort4 o;
        o.x = f2bf(v.x); o.y = f2bf(v.y); o.z = f2bf(v.z); o.w = f2bf(v.w);
        *(ushort4*)(xh + (long)row * 1024 + i) = o;
    }
#pragma unroll
    for (int o = 32; o; o >>= 1) dot += __shfl_down(dot, o);
    if (lane == 0) {
        float s = 1.f / (1.f + __expf(-5.f * dot)) + 1e-5f;
        sigma[row] = exp2f(s * 1.5849625007211562f) - 1.f;   // 3^s - 1
    }
}

// all three weights: W [D,D] f32 -> WT bf16 (WT[n][k] = W[k][n]); z selects
__global__ void wt_all(const float* __restrict__ Wq, const float* __restrict__ Wk,
                       const float* __restrict__ Wv,
                       ushort_t* __restrict__ WqkT, ushort_t* __restrict__ WvT)
{
    const float* W = blockIdx.z == 0 ? Wq : (blockIdx.z == 1 ? Wk : Wv);
    ushort_t* WT = (blockIdx.z == 2) ? WvT : (WqkT + (long)blockIdx.z * 1024 * 1024);
    __shared__ float s[64][65];
    const int tr = blockIdx.x * 64, tc = blockIdx.y * 64;
    const int t = threadIdx.x;
    const int r = t >> 4, c4 = (t & 15) * 4;
#pragma unroll
    for (int rr = r; rr < 64; rr += 16) {
        float4 v = *(const float4*)(W + (long)(tr + rr) * 1024 + tc + c4);
        s[rr][c4] = v.x; s[rr][c4 + 1] = v.y; s[rr][c4 + 2] = v.z; s[rr][c4 + 3] = v.w;
    }
    __syncthreads();
#pragma unroll
    for (int rr = r; rr < 64; rr += 16) {
        ushort4 o;
        o.x = f2bf(s[c4][rr]);     o.y = f2bf(s[c4 + 1][rr]);
        o.z = f2bf(s[c4 + 2][rr]); o.w = f2bf(s[c4 + 3][rr]);
        *(ushort4*)(WT + (long)(tc + rr) * 1024 + tr + c4) = o;
    }
}

// softmax over batch dim (8 values, stride NN)
__global__ void softmax_batch(const float* __restrict__ scores, ushort_t* __restrict__ S)
{
    const long idx = (long)blockIdx.x * 256 + threadIdx.x;
    float v[8], m = -1e30f;
#pragma unroll
    for (int b = 0; b < 8; ++b) { v[b] = scores[(long)b * NN + idx]; m = fmaxf(m, v[b]); }
    float sum = 0.f;
#pragma unroll
    for (int b = 0; b < 8; ++b) { v[b] = __expf(v[b] - m); sum += v[b]; }
    const float inv = 1.f / sum;
#pragma unroll
    for (int b = 0; b < 8; ++b) S[(long)b * NN + idx] = f2bf(v[b] * inv);
}

__global__ void prior_rowsum(const float* __restrict__ sigma, float* __restrict__ rowsum)
{
    const int row  = blockIdx.x * 4 + (threadIdx.x >> 6);
    const int lane = threadIdx.x & 63;
    const int i = row & 1023;
    const float sg = sigma[row];
    const float c = -0.5f / (sg * sg);
    float a = 0.f;
    for (int j = lane; j < 1024; j += 64) {
        float d = (float)(i - j);
        a += __expf(c * d * d);
    }
#pragma unroll
    for (int o = 32; o; o >>= 1) a += __shfl_down(a, o);
    if (lane == 0) rowsum[row] = (0.3989422804014327f / sg) * a;
}

__global__ void batch_reduce(const float* __restrict__ rowsum, float* __restrict__ batchsum)
{
    __shared__ float s[256];
    const int b = blockIdx.x, t = threadIdx.x;
    float a = 0.f;
    for (int i = t; i < 1024; i += 256) a += rowsum[b * 1024 + i];
    s[t] = a; __syncthreads();
    for (int o = 128; o; o >>= 1) { if (t < o) s[t] += s[t + o]; __syncthreads(); }
    if (t == 0) batchsum[b] = s[0];
}

__global__ void prior_write(const float* __restrict__ sigma, const float* __restrict__ batchsum,
                            float* __restrict__ P)
{
    const long idx = (long)blockIdx.x * 256 + threadIdx.x;
    const int b   = (int)(idx >> 20);
    const int rem = (int)(idx & (NN - 1));
    const int i = rem >> 10;
    const int j = rem & 1023;
    const float sg = sigma[(b << 10) + i];
    const float d = (float)(i - j);
    const float g = (0.3989422804014327f / sg) * __expf((-0.5f / (sg * sg)) * d * d);
    P[idx] = g / batchsum[b];
}

// ---------------------------------------------------------------------------
extern "C" void kernel_launch(void* const* d_in, const int* in_sizes, int n_in,
                              void* d_out, int out_size, void* d_ws, size_t ws_size,
                              hipStream_t stream)
{
    const float* x  = (const float*)d_in[0];
    const float* Wq = (const float*)d_in[1];
    const float* Wk = (const float*)d_in[2];
    const float* Wv = (const float*)d_in[3];
    const float* Ws = (const float*)d_in[4];
    float* Zout = (float*)d_out;
    float* Pout = Zout + 8 * ND;

    char* base = (char*)d_ws;
    size_t off = 0;
    auto alloc = [&](size_t bytes) {
        void* p = base + off;
        off = (off + bytes + 255) & ~(size_t)255;
        return p;
    };
    ushort_t* xh    = (ushort_t*)alloc(8192L * 1024 * 2);   // 16.78 MB
    ushort_t* WqkT  = (ushort_t*)alloc(2048L * 1024 * 2);   //  4.19 MB
    ushort_t* WvT   = (ushort_t*)alloc(1024L * 1024 * 2);   //  2.10 MB
    ushort_t* QKh   = (ushort_t*)alloc(8192L * 2048 * 2);   // 33.55 MB
    ushort_t* VTall = (ushort_t*)alloc(1024L * 8192 * 2);   // 16.78 MB
    float* sigma    = (float*)alloc(8192 * 4);
    float* rowsum   = (float*)alloc(8192 * 4);
    float* batchsum = (float*)alloc(64);
    // overlays: scores (f32) -> Pout half of d_out (dead until prior_write);
    //           S (bf16)     -> xh (dead after VT gemm)
    float*    scores = Pout;
    ushort_t* Sh     = xh;

    // 1. x -> bf16 + sigma (fused)
    cvt_x_sigma<<<2048, 256, 0, stream>>>(x, Ws, xh, sigma);
    // 2. all weight transposes (Wq,Wk stacked; Wv separate)
    wt_all<<<dim3(16, 16, 3), 256, 0, stream>>>(Wq, Wk, Wv, WqkT, WvT);
    // 3. [Q|K] = x @ [Wq|Wk]   (M=8192, N=2048) -> QKh ld 2048
    gemm3b<1><<<dim3(64, 8, 1), 512, 0, stream>>>(
        xh, WqkT, QKh, 1024, 1024, 2048, 0, 0, 0, 1.f);
    // 4. VT = Wv^T x^T         (M=1024, N=8192) -> VTall ld 8192
    gemm3b<1><<<dim3(8, 32, 1), 512, 0, stream>>>(
        WvT, xh, VTall, 1024, 1024, 8192, 0, 0, 0, 1.f);
    // 5. scores = Q K^T / 32   (per batch, f32 -> Pout scratch)
    gemm3b<0><<<dim3(8, 4, 8), 512, 0, stream>>>(
        QKh, QKh + 1024, scores, 2048, 2048, 1024,
        1024L * 2048, 1024L * 2048, NN, 0.03125f);
    // 6. softmax over batch -> S (bf16, overlays xh)
    softmax_batch<<<4096, 256, 0, stream>>>(scores, Sh);
    // 7. Z = S V               (per batch, f32 -> d_out)
    gemm3b<0><<<dim3(8, 4, 8), 512, 0, stream>>>(
        Sh, VTall, Zout, 1024, 8192, 1024,
        NN, 1024, ND, 1.f);
    // 8-10. prior P (fp32 exact, deterministic)
    prior_rowsum<<<2048, 256, 0, stream>>>(sigma, rowsum);
    batch_reduce<<<8, 256, 0, stream>>>(rowsum, batchsum);
    prior_write<<<32768, 256, 0, stream>>>(sigma, batchsum, Pout);
}